// Round 7
// baseline (2318.039 us; speedup 1.0000x reference)
//
#include <hip/hip_runtime.h>
#include <stdint.h>

#define DEV __device__ __forceinline__

using f32x4  = __attribute__((ext_vector_type(4))) float;
using bf16x8 = __attribute__((ext_vector_type(8))) short;
typedef unsigned short u16;
typedef unsigned int   u32;

typedef const __attribute__((address_space(1))) void* gptr_t;
typedef __attribute__((address_space(3))) void*       lptr_t;

DEV u16 f2bf(float f) {               // RTNE float -> bf16 bits
  union { float f; u32 u; } v; v.f = f;
  u32 lsb = (v.u >> 16) & 1u;
  v.u += 0x7fffu + lsb;
  return (u16)(v.u >> 16);
}
DEV float bf2f(u16 h) {
  union { u32 u; float f; } v; v.u = ((u32)h) << 16;
  return v.f;
}
DEV void async16(void* lds, const void* g) {
  __builtin_amdgcn_global_load_lds((gptr_t)(uintptr_t)g,
                                   (lptr_t)(u32)(uintptr_t)lds, 16, 0, 0);
}
// monotone float->uint key (ascending order preserved)
DEV u32 fkey(float v) {
  u32 u = __float_as_uint(v);
  return u ^ ((u & 0x80000000u) ? 0xFFFFFFFFu : 0x80000000u);
}

// bit-exact replica of np.einsum fp32 inner dot (sum_of_products_contig_outstride0_two,
// SSE-128 baseline, no FMA): 4 lanes (j === l mod 4); per 16-block reversed chain
// vac_l = x[j+l]w[j+l] + (x[j+4+l]w[j+4+l] + (x[j+8+l]w[j+8+l] + (x[j+12+l]w[j+12+l] + vac_l)));
// combine (v0+v1)+(v2+v3) via SSE3 hadd. 1024 = 64 blocks, no tail.
DEV float replica_dot(const float* __restrict__ xr, const float* __restrict__ wr) {
  float v0 = 0.f, v1 = 0.f, v2 = 0.f, v3 = 0.f;
  for (int j = 0; j < 1024; j += 16) {
    float t0 = __fadd_rn(__fmul_rn(xr[j + 12], wr[j + 12]), v0);
    float t1 = __fadd_rn(__fmul_rn(xr[j + 13], wr[j + 13]), v1);
    float t2 = __fadd_rn(__fmul_rn(xr[j + 14], wr[j + 14]), v2);
    float t3 = __fadd_rn(__fmul_rn(xr[j + 15], wr[j + 15]), v3);
    t0 = __fadd_rn(__fmul_rn(xr[j + 8],  wr[j + 8]),  t0);
    t1 = __fadd_rn(__fmul_rn(xr[j + 9],  wr[j + 9]),  t1);
    t2 = __fadd_rn(__fmul_rn(xr[j + 10], wr[j + 10]), t2);
    t3 = __fadd_rn(__fmul_rn(xr[j + 11], wr[j + 11]), t3);
    t0 = __fadd_rn(__fmul_rn(xr[j + 4],  wr[j + 4]),  t0);
    t1 = __fadd_rn(__fmul_rn(xr[j + 5],  wr[j + 5]),  t1);
    t2 = __fadd_rn(__fmul_rn(xr[j + 6],  wr[j + 6]),  t2);
    t3 = __fadd_rn(__fmul_rn(xr[j + 7],  wr[j + 7]),  t3);
    v0 = __fadd_rn(__fmul_rn(xr[j + 0],  wr[j + 0]),  t0);
    v1 = __fadd_rn(__fmul_rn(xr[j + 1],  wr[j + 1]),  t1);
    v2 = __fadd_rn(__fmul_rn(xr[j + 2],  wr[j + 2]),  t2);
    v3 = __fadd_rn(__fmul_rn(xr[j + 3],  wr[j + 3]),  t3);
  }
  return __fadd_rn(__fadd_rn(v0, v1), __fadd_rn(v2, v3));
}

// ---------------- split kernels: fp32 -> bf16 hi (+lo) ----------------
__global__ __launch_bounds__(256) void split2_kernel(const float* __restrict__ src,
                                                     u16* __restrict__ hi, u16* __restrict__ lo, int n) {
  int i = blockIdx.x * 256 + threadIdx.x;
  if (i >= n) return;
  float v = src[i];
  u16 h = f2bf(v);
  hi[i] = h;
  lo[i] = f2bf(v - bf2f(h));
}
__global__ __launch_bounds__(256) void split1_kernel(const float* __restrict__ src,
                                                     u16* __restrict__ hi, int n) {
  int i = blockIdx.x * 256 + threadIdx.x;
  if (i >= n) return;
  hi[i] = f2bf(src[i]);
}

// ------- GEMM 3-pass split precision: C = A*B^T fp32 out (selection-grade z) -------
template<int BK>
__global__ __launch_bounds__(256) void gemm3_kernel(
    const u16* __restrict__ Ahi, const u16* __restrict__ Alo,
    const u16* __restrict__ Bhi, const u16* __restrict__ Blo,
    float* __restrict__ C, int N, int K)
{
  constexpr int TILE = 128 * BK;
  __shared__ u16 smem[4 * TILE];
  u16* sAhi = smem;
  u16* sAlo = smem + TILE;
  u16* sBhi = smem + 2 * TILE;
  u16* sBlo = smem + 3 * TILE;

  const int tid  = threadIdx.x;
  const int lane = tid & 63;
  const int wave = tid >> 6;
  const int wr = wave >> 1, wc = wave & 1;
  const int m0 = blockIdx.y * 128, n0 = blockIdx.x * 128;

  f32x4 acc[4][4] = {};
  constexpr int SPR   = BK / 8;
  constexpr int ITERS = (128 * SPR) / 256;

  for (int k0 = 0; k0 < K; k0 += BK) {
#pragma unroll
    for (int i = 0; i < ITERS; ++i) {
      const int slot = i * 256 + tid;
      const int r = slot / SPR, cc = slot % SPR;
      const int uni = (i * 256 + wave * 64) * 8;
      const size_t ga = (size_t)(m0 + r) * K + k0 + cc * 8;
      const size_t gb = (size_t)(n0 + r) * K + k0 + cc * 8;
      async16(sAhi + uni, Ahi + ga);
      async16(sBhi + uni, Bhi + gb);
      async16(sAlo + uni, Alo + ga);
      async16(sBlo + uni, Blo + gb);
    }
    __syncthreads();

#pragma unroll
    for (int ks = 0; ks < BK / 32; ++ks) {
      const int kb = ks * 32 + (lane >> 4) * 8;
      bf16x8 ah[4], bh[4], al[4], bl[4];
#pragma unroll
      for (int i = 0; i < 4; ++i) {
        const int ra = wr * 64 + i * 16 + (lane & 15);
        const int rb = wc * 64 + i * 16 + (lane & 15);
        ah[i] = *(const bf16x8*)&sAhi[ra * BK + kb];
        bh[i] = *(const bf16x8*)&sBhi[rb * BK + kb];
        al[i] = *(const bf16x8*)&sAlo[ra * BK + kb];
        bl[i] = *(const bf16x8*)&sBlo[rb * BK + kb];
      }
#pragma unroll
      for (int mi = 0; mi < 4; ++mi)
#pragma unroll
        for (int ni = 0; ni < 4; ++ni) {
          acc[mi][ni] = __builtin_amdgcn_mfma_f32_16x16x32_bf16(ah[mi], bh[ni], acc[mi][ni], 0, 0, 0);
          acc[mi][ni] = __builtin_amdgcn_mfma_f32_16x16x32_bf16(ah[mi], bl[ni], acc[mi][ni], 0, 0, 0);
          acc[mi][ni] = __builtin_amdgcn_mfma_f32_16x16x32_bf16(al[mi], bh[ni], acc[mi][ni], 0, 0, 0);
        }
    }
    __syncthreads();
  }

#pragma unroll
  for (int mi = 0; mi < 4; ++mi) {
    const int rbase = m0 + wr * 64 + mi * 16 + (lane >> 4) * 4;
#pragma unroll
    for (int ni = 0; ni < 4; ++ni) {
      const int col = n0 + wc * 64 + ni * 16 + (lane & 15);
#pragma unroll
      for (int r2 = 0; r2 < 4; ++r2)
        C[(size_t)(rbase + r2) * N + col] = acc[mi][ni][r2];
    }
  }
}

// ------- GEMM 1-pass bf16: C = A*B^T fp32 out (dense-grade gate / down-proj) -------
template<int BK>
__global__ __launch_bounds__(256) void gemm_bt(
    const u16* __restrict__ A, const u16* __restrict__ B,
    float* __restrict__ C, int N, int K)
{
  constexpr int TILE = 128 * BK;
  __shared__ u16 smem[2 * TILE];
  u16* sA = smem;
  u16* sB = smem + TILE;

  const int tid  = threadIdx.x;
  const int lane = tid & 63;
  const int wave = tid >> 6;
  const int wr = wave >> 1, wc = wave & 1;
  const int m0 = blockIdx.y * 128, n0 = blockIdx.x * 128;

  f32x4 acc[4][4] = {};
  constexpr int SPR   = BK / 8;
  constexpr int ITERS = (128 * SPR) / 256;

  for (int k0 = 0; k0 < K; k0 += BK) {
#pragma unroll
    for (int i = 0; i < ITERS; ++i) {
      const int slot = i * 256 + tid;
      const int r = slot / SPR, cc = slot % SPR;
      const int uni = (i * 256 + wave * 64) * 8;
      async16(sA + uni, A + (size_t)(m0 + r) * K + k0 + cc * 8);
      async16(sB + uni, B + (size_t)(n0 + r) * K + k0 + cc * 8);
    }
    __syncthreads();

#pragma unroll
    for (int ks = 0; ks < BK / 32; ++ks) {
      const int kb = ks * 32 + (lane >> 4) * 8;
      bf16x8 a[4], b[4];
#pragma unroll
      for (int i = 0; i < 4; ++i) {
        a[i] = *(const bf16x8*)&sA[(wr * 64 + i * 16 + (lane & 15)) * BK + kb];
        b[i] = *(const bf16x8*)&sB[(wc * 64 + i * 16 + (lane & 15)) * BK + kb];
      }
#pragma unroll
      for (int mi = 0; mi < 4; ++mi)
#pragma unroll
        for (int ni = 0; ni < 4; ++ni)
          acc[mi][ni] = __builtin_amdgcn_mfma_f32_16x16x32_bf16(a[mi], b[ni], acc[mi][ni], 0, 0, 0);
    }
    __syncthreads();
  }

#pragma unroll
  for (int mi = 0; mi < 4; ++mi) {
    const int rbase = m0 + wr * 64 + mi * 16 + (lane >> 4) * 4;
#pragma unroll
    for (int ni = 0; ni < 4; ++ni) {
      const int col = n0 + wc * 64 + ni * 16 + (lane & 15);
#pragma unroll
      for (int r2 = 0; r2 < 4; ++r2)
        C[(size_t)(rbase + r2) * N + col] = acc[mi][ni][r2];
    }
  }
}

// radix-select the k-th largest key in keys[0..4095]; returns key, sets ties_rem
__device__ u32 radix_kth(const u32* keys, u32* hist, u32* s_bin, u32* s_kk,
                         int tid, u32 kk0, u32& ties_rem) {
  u32 prefix = 0, kk = kk0;
  for (int sh = 24; sh >= 0; sh -= 8) {
    hist[tid] = 0;
    __syncthreads();
    const u32 maskhi = (sh == 24) ? 0u : (0xFFFFFFFFu << (sh + 8));
    for (int f = tid; f < 4096; f += 256) {
      const u32 u = keys[f];
      if ((u & maskhi) == prefix) atomicAdd(&hist[(u >> sh) & 255], 1u);
    }
    __syncthreads();
    if (tid == 0) {
      u32 cum = 0;
      for (int b = 255; b >= 0; --b) {
        const u32 c = hist[b];
        if (cum + c >= kk) { *s_bin = (u32)b; *s_kk = kk - cum; break; }
        cum += c;
      }
    }
    __syncthreads();
    prefix |= (*s_bin) << sh;
    kk = *s_kk;
    __syncthreads();
  }
  ties_rem = kk;
  return prefix;
}

// ---------------- per-row top-k: GEMM-z band + replica keys (R6-equivalent) ----------------
// 1) radix kth on fkey(GEMM z)  -> tau_z  (z err ~3e-6; boundary-relevant channels
//    provably within +/-4e-5 of tau_z)
// 2) band = |z - tau_z| <= 2e-4 -> exact numpy-replica z + f64-silu fp32 keys
//    non-band -> fp32-silu approx keys (distance to kth key >> key error)
// 3) radix kth on act keys, select > kth, fill ties lowest-index-first (== R6 logic)
__global__ __launch_bounds__(256) void select3_kernel(
    const float* __restrict__ z, const float* __restrict__ g,
    const float* __restrict__ xin, const float* __restrict__ W1,
    u16* __restrict__ sbuf, const int* __restrict__ kptr)
{
  const int DFF = 4096, DM = 1024;
  const int row = blockIdx.x, tid = threadIdx.x;
  const int k = *kptr;

  __shared__ float zf[4096];
  __shared__ float acts[4096];
  __shared__ u32 keys[4096];
  __shared__ float xrow[1024];
  __shared__ u32 hist[256];
  __shared__ u32 s_bin, s_kk;
  __shared__ int s_nb, s_T;
  __shared__ int band_idx[64];
  __shared__ float band_z[64];
  __shared__ int tie_idx[64];
  __shared__ unsigned char tie_sel[64];

  const float* zr = z + (size_t)row * DFF;
  for (int f = tid; f < DFF; f += 256) { zf[f] = zr[f]; keys[f] = fkey(zr[f]); }
  for (int j = tid; j < DM; j += 256) xrow[j] = xin[(size_t)row * DM + j];
  __syncthreads();

  // radix #1: kth largest of our GEMM z
  u32 dummy;
  const u32 zkth = radix_kth(keys, hist, &s_bin, &s_kk, tid, (u32)k, dummy);
  const u32 zb = (zkth & 0x80000000u) ? (zkth ^ 0x80000000u) : ~zkth;
  const float tauz = __uint_as_float(zb);
  const float BANDW = 2e-4f;

  if (tid == 0) s_nb = 0;
  __syncthreads();
  for (int f = tid; f < DFF; f += 256) {
    if (fabsf(zf[f] - tauz) <= BANDW) {
      const int p = atomicAdd(&s_nb, 1);
      if (p < 64) band_idx[p] = f;
    }
  }
  __syncthreads();
  const int nb = s_nb;

  // approx act keys for all channels (fp32 silu of GEMM z)
  for (int f = tid; f < DFF; f += 256) {
    const float zv = zf[f];
    const float act = zv / (1.f + expf(-zv));
    acts[f] = act;
    keys[f] = fkey(act);
  }
  __syncthreads();

  if (nb <= 64) {
    // exact replica keys for band channels
    if (tid < nb) {
      const int f = band_idx[tid];
      const float zrep = replica_dot(xrow, W1 + (size_t)f * DM);
      const double zd = (double)zrep;
      const float a = (float)(zd / (1.0 + exp(-zd)));
      acts[f] = a;
      keys[f] = fkey(a);
    }
  } else {
    // fallback (P ~ 0): exact replica for the whole row
    for (int f = tid; f < DFF; f += 256) {
      const float zrep = replica_dot(xrow, W1 + (size_t)f * DM);
      const double zd = (double)zrep;
      const float a = (float)(zd / (1.0 + exp(-zd)));
      acts[f] = a;
      keys[f] = fkey(a);
    }
  }
  __syncthreads();

  // radix #2: kth largest act key (reference comparison key)
  u32 ties;
  const u32 kth = radix_kth(keys, hist, &s_bin, &s_kk, tid, (u32)k, ties);
  const int take_ties = (int)ties;

  // collect ties at kth
  if (tid == 0) s_T = 0;
  __syncthreads();
  for (int f = tid; f < DFF; f += 256) {
    if (keys[f] == kth) {
      const int p = atomicAdd(&s_T, 1);
      if (p < 64) tie_idx[p] = f;
    }
  }
  __syncthreads();
  const int T = s_T;

  if (T <= 64) {
    if (tid == 0) {
      for (int i = 0; i < T; ++i) tie_sel[i] = 0;
      for (int t = 0; t < take_ties; ++t) {
        int best = -1;
        for (int i = 0; i < T; ++i)
          if (!tie_sel[i] && (best < 0 || tie_idx[i] < tie_idx[best])) best = i;
        if (best >= 0) tie_sel[best] = 1;
      }
    }
    __syncthreads();
    const float* grow = g + (size_t)row * DFF;
    for (int f = tid; f < DFF; f += 256) {
      const u32 u = keys[f];
      bool sel = (u > kth);
      if (!sel && u == kth) {
        for (int i = 0; i < T; ++i)
          if (tie_idx[i] == f) { sel = (tie_sel[i] != 0); break; }
      }
      const float sval = sel ? acts[f] * grow[f] : 0.f;
      sbuf[(size_t)row * DFF + f] = f2bf(sval);
    }
  } else {
    if (tid == 0) {
      const float* grow = g + (size_t)row * DFF;
      int taken = 0;
      for (int f = 0; f < DFF; ++f) {
        bool sel = (keys[f] > kth);
        if (!sel && keys[f] == kth && taken < take_ties) { sel = true; ++taken; }
        sbuf[(size_t)row * DFF + f] = f2bf(sel ? acts[f] * grow[f] : 0.f);
      }
    }
  }
}

// ---------------- launch ----------------
extern "C" void kernel_launch(void* const* d_in, const int* in_sizes, int n_in,
                              void* d_out, int out_size, void* d_ws, size_t ws_size,
                              hipStream_t stream)
{
  const float* x  = (const float*)d_in[0];
  const float* W1 = (const float*)d_in[1];
  const float* W2 = (const float*)d_in[2];
  const float* Wo = (const float*)d_in[3];
  const int* kptr = (const int*)d_in[4];

  const int DM = 1024, DF = 4096;
  const int M = in_sizes[0] / DM;   // 8192 rows
  const size_t nX = (size_t)M * DM, nW = (size_t)DF * DM, nWo = (size_t)DM * DF;

  // fixed split buffers
  char* w = (char*)d_ws;
  u16* x_hi  = (u16*)w;  w += nX * 2;
  u16* x_lo  = (u16*)w;  w += nX * 2;
  u16* W1_hi = (u16*)w;  w += nW * 2;
  u16* W1_lo = (u16*)w;  w += nW * 2;
  u16* W2_hi = (u16*)w;  w += nW * 2;
  u16* Wo_hi = (u16*)w;  w += nWo * 2;
  const size_t fixed_bytes = (size_t)(w - (char*)d_ws);

  // per-chunk activations: z(4) + g(4) + s(2) = 10 B/elem
  int nch = 1;
  while (nch < 64) {
    const size_t per = (size_t)(M / nch) * DF * 10;
    if (fixed_bytes + per <= ws_size) break;
    nch *= 2;
  }
  const int Mc = M / nch;

  float* zbuf = (float*)w;
  float* gbuf = (float*)(w + (size_t)Mc * DF * 4);
  u16*   sbuf = (u16*)(w + (size_t)Mc * DF * 8);

  split2_kernel<<<dim3((int)((nX + 255) / 256)), 256, 0, stream>>>(x, x_hi, x_lo, (int)nX);
  split2_kernel<<<dim3((int)((nW + 255) / 256)), 256, 0, stream>>>(W1, W1_hi, W1_lo, (int)nW);
  split1_kernel<<<dim3((int)((nW + 255) / 256)), 256, 0, stream>>>(W2, W2_hi, (int)nW);
  split1_kernel<<<dim3((int)((nWo + 255) / 256)), 256, 0, stream>>>(Wo, Wo_hi, (int)nWo);

  for (int ch = 0; ch < nch; ++ch) {
    const size_t ro = (size_t)ch * Mc;
    // z = x @ W1^T (3-pass split precision, err ~3e-6: selection-grade)
    gemm3_kernel<32><<<dim3(DF / 128, Mc / 128), 256, 0, stream>>>(
        x_hi + ro * DM, x_lo + ro * DM, W1_hi, W1_lo, zbuf, DF, DM);
    // gate = x @ W2^T (1-pass bf16)
    gemm_bt<64><<<dim3(DF / 128, Mc / 128), 256, 0, stream>>>(
        x_hi + ro * DM, W2_hi, gbuf, DF, DM);
    // top-k: band replica keys + act-key radix + stable ties (R6-equivalent)
    select3_kernel<<<dim3(Mc), 256, 0, stream>>>(
        zbuf, gbuf, x + ro * DM, W1, sbuf, kptr);
    // out = s @ Wo^T (1-pass bf16)
    gemm_bt<64><<<dim3(DM / 128, Mc / 128), 256, 0, stream>>>(
        sbuf, Wo_hi, (float*)d_out + ro * DM, DM, DF);
  }
}

// Round 8
// 920.017 us; speedup vs baseline: 2.5196x; 2.5196x over previous
//
#include <hip/hip_runtime.h>
#include <stdint.h>

#define DEV __device__ __forceinline__

using f32x4  = __attribute__((ext_vector_type(4))) float;
using bf16x8 = __attribute__((ext_vector_type(8))) short;
typedef unsigned short u16;
typedef unsigned int   u32;

typedef const __attribute__((address_space(1))) void* gptr_t;
typedef __attribute__((address_space(3))) void*       lptr_t;

DEV u16 f2bf(float f) {               // RTNE float -> bf16 bits
  union { float f; u32 u; } v; v.f = f;
  u32 lsb = (v.u >> 16) & 1u;
  v.u += 0x7fffu + lsb;
  return (u16)(v.u >> 16);
}
DEV float bf2f(u16 h) {
  union { u32 u; float f; } v; v.u = ((u32)h) << 16;
  return v.f;
}
DEV void async16(void* lds, const void* g) {
  __builtin_amdgcn_global_load_lds((gptr_t)(uintptr_t)g,
                                   (lptr_t)(u32)(uintptr_t)lds, 16, 0, 0);
}
// monotone float->uint key (ascending order preserved)
DEV u32 fkey(float v) {
  u32 u = __float_as_uint(v);
  return u ^ ((u & 0x80000000u) ? 0xFFFFFFFFu : 0x80000000u);
}
DEV float unfkey(u32 key) {
  const u32 ub = (key & 0x80000000u) ? (key ^ 0x80000000u) : ~key;
  return __uint_as_float(ub);
}

// bit-exact replica of np.einsum fp32 inner dot (sum_of_products_contig_outstride0_two,
// SSE-128 baseline, no FMA): 4 lanes (j === l mod 4); per 16-block reversed chain;
// combine (v0+v1)+(v2+v3) via SSE3 hadd. 1024 = 64 blocks, no tail.
DEV float replica_dot(const float* __restrict__ xr, const float* __restrict__ wr) {
  float v0 = 0.f, v1 = 0.f, v2 = 0.f, v3 = 0.f;
  for (int j = 0; j < 1024; j += 16) {
    float t0 = __fadd_rn(__fmul_rn(xr[j + 12], wr[j + 12]), v0);
    float t1 = __fadd_rn(__fmul_rn(xr[j + 13], wr[j + 13]), v1);
    float t2 = __fadd_rn(__fmul_rn(xr[j + 14], wr[j + 14]), v2);
    float t3 = __fadd_rn(__fmul_rn(xr[j + 15], wr[j + 15]), v3);
    t0 = __fadd_rn(__fmul_rn(xr[j + 8],  wr[j + 8]),  t0);
    t1 = __fadd_rn(__fmul_rn(xr[j + 9],  wr[j + 9]),  t1);
    t2 = __fadd_rn(__fmul_rn(xr[j + 10], wr[j + 10]), t2);
    t3 = __fadd_rn(__fmul_rn(xr[j + 11], wr[j + 11]), t3);
    t0 = __fadd_rn(__fmul_rn(xr[j + 4],  wr[j + 4]),  t0);
    t1 = __fadd_rn(__fmul_rn(xr[j + 5],  wr[j + 5]),  t1);
    t2 = __fadd_rn(__fmul_rn(xr[j + 6],  wr[j + 6]),  t2);
    t3 = __fadd_rn(__fmul_rn(xr[j + 7],  wr[j + 7]),  t3);
    v0 = __fadd_rn(__fmul_rn(xr[j + 0],  wr[j + 0]),  t0);
    v1 = __fadd_rn(__fmul_rn(xr[j + 1],  wr[j + 1]),  t1);
    v2 = __fadd_rn(__fmul_rn(xr[j + 2],  wr[j + 2]),  t2);
    v3 = __fadd_rn(__fmul_rn(xr[j + 3],  wr[j + 3]),  t3);
  }
  return __fadd_rn(__fadd_rn(v0, v1), __fadd_rn(v2, v3));
}

// ---------------- split kernels: fp32 -> bf16 hi (+lo) ----------------
__global__ __launch_bounds__(256) void split2_kernel(const float* __restrict__ src,
                                                     u16* __restrict__ hi, u16* __restrict__ lo, int n) {
  int i = blockIdx.x * 256 + threadIdx.x;
  if (i >= n) return;
  float v = src[i];
  u16 h = f2bf(v);
  hi[i] = h;
  lo[i] = f2bf(v - bf2f(h));
}
__global__ __launch_bounds__(256) void split1_kernel(const float* __restrict__ src,
                                                     u16* __restrict__ hi, int n) {
  int i = blockIdx.x * 256 + threadIdx.x;
  if (i >= n) return;
  hi[i] = f2bf(src[i]);
}

// ------- split-precision z GEMM as ONE K'=3K 1-pass GEMM -------
// z = Ah*Bh + Ah*Bl + Al*Bh == [Ah|Ah|Al] . [Bh|Bl|Bh] over concatenated K.
// Standard 128x128 tile / BK=64 / 2-buffer structure; per K-step the staging
// selects segment pointers. fp32 AGPR accumulation (reassoc ~1e-7, harmless).
template<int BK>
__global__ __launch_bounds__(256) void gemmz_kernel(
    const u16* __restrict__ Ahi, const u16* __restrict__ Alo,
    const u16* __restrict__ Bhi, const u16* __restrict__ Blo,
    float* __restrict__ C, int N, int K)
{
  constexpr int TILE = 128 * BK;
  __shared__ u16 smem[2 * TILE];
  u16* sA = smem;
  u16* sB = smem + TILE;

  const int tid  = threadIdx.x;
  const int lane = tid & 63;
  const int wave = tid >> 6;
  const int wr = wave >> 1, wc = wave & 1;
  const int m0 = blockIdx.y * 128, n0 = blockIdx.x * 128;

  f32x4 acc[4][4] = {};
  constexpr int SPR   = BK / 8;
  constexpr int ITERS = (128 * SPR) / 256;

  for (int kt = 0; kt < 3 * K; kt += BK) {
    const int seg = kt / K;
    const int kl  = kt - seg * K;
    const u16* __restrict__ Asrc = (seg == 2) ? Alo : Ahi;
    const u16* __restrict__ Bsrc = (seg == 1) ? Blo : Bhi;
#pragma unroll
    for (int i = 0; i < ITERS; ++i) {
      const int slot = i * 256 + tid;
      const int r = slot / SPR, cc = slot % SPR;
      const int uni = (i * 256 + wave * 64) * 8;
      async16(sA + uni, Asrc + (size_t)(m0 + r) * K + kl + cc * 8);
      async16(sB + uni, Bsrc + (size_t)(n0 + r) * K + kl + cc * 8);
    }
    __syncthreads();

#pragma unroll
    for (int ks = 0; ks < BK / 32; ++ks) {
      const int kb = ks * 32 + (lane >> 4) * 8;
      bf16x8 a[4], b[4];
#pragma unroll
      for (int i = 0; i < 4; ++i) {
        a[i] = *(const bf16x8*)&sA[(wr * 64 + i * 16 + (lane & 15)) * BK + kb];
        b[i] = *(const bf16x8*)&sB[(wc * 64 + i * 16 + (lane & 15)) * BK + kb];
      }
#pragma unroll
      for (int mi = 0; mi < 4; ++mi)
#pragma unroll
        for (int ni = 0; ni < 4; ++ni)
          acc[mi][ni] = __builtin_amdgcn_mfma_f32_16x16x32_bf16(a[mi], b[ni], acc[mi][ni], 0, 0, 0);
    }
    __syncthreads();
  }

#pragma unroll
  for (int mi = 0; mi < 4; ++mi) {
    const int rbase = m0 + wr * 64 + mi * 16 + (lane >> 4) * 4;
#pragma unroll
    for (int ni = 0; ni < 4; ++ni) {
      const int col = n0 + wc * 64 + ni * 16 + (lane & 15);
#pragma unroll
      for (int r2 = 0; r2 < 4; ++r2)
        C[(size_t)(rbase + r2) * N + col] = acc[mi][ni][r2];
    }
  }
}

// ------- GEMM 1-pass bf16: C = A*B^T fp32 out (dense-grade gate / down-proj) -------
template<int BK>
__global__ __launch_bounds__(256) void gemm_bt(
    const u16* __restrict__ A, const u16* __restrict__ B,
    float* __restrict__ C, int N, int K)
{
  constexpr int TILE = 128 * BK;
  __shared__ u16 smem[2 * TILE];
  u16* sA = smem;
  u16* sB = smem + TILE;

  const int tid  = threadIdx.x;
  const int lane = tid & 63;
  const int wave = tid >> 6;
  const int wr = wave >> 1, wc = wave & 1;
  const int m0 = blockIdx.y * 128, n0 = blockIdx.x * 128;

  f32x4 acc[4][4] = {};
  constexpr int SPR   = BK / 8;
  constexpr int ITERS = (128 * SPR) / 256;

  for (int k0 = 0; k0 < K; k0 += BK) {
#pragma unroll
    for (int i = 0; i < ITERS; ++i) {
      const int slot = i * 256 + tid;
      const int r = slot / SPR, cc = slot % SPR;
      const int uni = (i * 256 + wave * 64) * 8;
      async16(sA + uni, A + (size_t)(m0 + r) * K + k0 + cc * 8);
      async16(sB + uni, B + (size_t)(n0 + r) * K + k0 + cc * 8);
    }
    __syncthreads();

#pragma unroll
    for (int ks = 0; ks < BK / 32; ++ks) {
      const int kb = ks * 32 + (lane >> 4) * 8;
      bf16x8 a[4], b[4];
#pragma unroll
      for (int i = 0; i < 4; ++i) {
        a[i] = *(const bf16x8*)&sA[(wr * 64 + i * 16 + (lane & 15)) * BK + kb];
        b[i] = *(const bf16x8*)&sB[(wc * 64 + i * 16 + (lane & 15)) * BK + kb];
      }
#pragma unroll
      for (int mi = 0; mi < 4; ++mi)
#pragma unroll
        for (int ni = 0; ni < 4; ++ni)
          acc[mi][ni] = __builtin_amdgcn_mfma_f32_16x16x32_bf16(a[mi], b[ni], acc[mi][ni], 0, 0, 0);
    }
    __syncthreads();
  }

#pragma unroll
  for (int mi = 0; mi < 4; ++mi) {
    const int rbase = m0 + wr * 64 + mi * 16 + (lane >> 4) * 4;
#pragma unroll
    for (int ni = 0; ni < 4; ++ni) {
      const int col = n0 + wc * 64 + ni * 16 + (lane & 15);
#pragma unroll
      for (int r2 = 0; r2 < 4; ++r2)
        C[(size_t)(rbase + r2) * N + col] = acc[mi][ni][r2];
    }
  }
}

// ---------------- per-row top-k: register bisection + band replica ----------------
// z row lives in registers (16/thread). kth-largest our-z key found by 32-step MSB
// bisection (register compares + shuffle reduce; NO histograms/atomic storms).
// Selection semantics == R6/R7 (validated): D = {z-tau > 2e-4} definite-selected;
// band |z-tau| <= 2e-4 re-ranked by exact numpy-replica fp32 act keys, stable
// index tie-break, top (k-|D|) taken.
__global__ __launch_bounds__(256) void select4_kernel(
    const float* __restrict__ z, const float* __restrict__ g,
    const float* __restrict__ xin, const float* __restrict__ W1,
    u16* __restrict__ sbuf, const int* __restrict__ kptr)
{
  const int row = blockIdx.x, tid = threadIdx.x;
  const int lane = tid & 63, wave = tid >> 6;
  const int k = *kptr;

  __shared__ float xrow[1024];
  __shared__ int wsum[33][4];
  __shared__ unsigned char flag[4096];
  __shared__ int s_nb;
  __shared__ int band_idx[256];
  __shared__ u32 band_key[256];

  // load this thread's 16 z values (coalesced float4) + keys
  float zreg[16];
  u32 kreg[16];
  const float* zr = z + (size_t)row * 4096;
#pragma unroll
  for (int i = 0; i < 4; ++i) {
    const float4 v = *(const float4*)&zr[i * 1024 + tid * 4];
    zreg[i * 4 + 0] = v.x; zreg[i * 4 + 1] = v.y;
    zreg[i * 4 + 2] = v.z; zreg[i * 4 + 3] = v.w;
  }
#pragma unroll
  for (int i = 0; i < 16; ++i) kreg[i] = fkey(zreg[i]);

  for (int j = tid; j < 1024; j += 256) xrow[j] = xin[(size_t)row * 1024 + j];
  for (int f = tid; f < 4096; f += 256) flag[f] = 0;
  if (tid == 0) s_nb = 0;
  __syncthreads();

  // 32-step MSB bisection for kth largest key
  u32 prefix = 0;
  for (int bit = 31; bit >= 0; --bit) {
    const u32 c = prefix | (1u << bit);
    int cnt = 0;
#pragma unroll
    for (int i = 0; i < 16; ++i) cnt += (kreg[i] >= c) ? 1 : 0;
    for (int off = 32; off; off >>= 1) cnt += __shfl_xor(cnt, off);
    if (lane == 0) wsum[bit][wave] = cnt;
    __syncthreads();
    const int tot = wsum[bit][0] + wsum[bit][1] + wsum[bit][2] + wsum[bit][3];
    if (tot >= k) prefix = c;
  }
  const float tau = unfkey(prefix);
  const float BANDW = 2e-4f;

  // D flags (definite), band gather, |D| count
  int cntD = 0;
#pragma unroll
  for (int i = 0; i < 16; ++i) {
    const int f = (i >> 2) * 1024 + tid * 4 + (i & 3);
    const float d = zreg[i] - tau;
    if (d > BANDW) { flag[f] = 1; ++cntD; }
    else if (d >= -BANDW) {
      const int p = atomicAdd(&s_nb, 1);
      if (p < 256) band_idx[p] = f;
    }
  }
  for (int off = 32; off; off >>= 1) cntD += __shfl_xor(cntD, off);
  if (lane == 0) wsum[32][wave] = cntD;
  __syncthreads();
  const int D = wsum[32][0] + wsum[32][1] + wsum[32][2] + wsum[32][3];
  const int nb = (s_nb < 256) ? s_nb : 256;
  const int need = k - D;

  // exact replica act keys for band channels
  for (int i = tid; i < nb; i += 256) {
    const int f = band_idx[i];
    const float zrep = replica_dot(xrow, W1 + (size_t)f * 1024);
    const double zd = (double)zrep;
    band_key[i] = fkey((float)(zd / (1.0 + exp(-zd))));
  }
  __syncthreads();

  // stable rank (exact key desc, index asc); select rank < need
  for (int i = tid; i < nb; i += 256) {
    const u32 ki = band_key[i];
    const int fi = band_idx[i];
    int rank = 0;
    for (int j = 0; j < nb; ++j) {
      const u32 kj = band_key[j];
      rank += (kj > ki || (kj == ki && band_idx[j] < fi)) ? 1 : 0;
    }
    if (rank < need) flag[fi] = 1;
  }
  __syncthreads();

  // write s = silu(z) * gate for selected channels (bf16)
  const float* gr = g + (size_t)row * 4096;
  u16* srow = sbuf + (size_t)row * 4096;
#pragma unroll
  for (int i = 0; i < 4; ++i) {
    const float4 gv = *(const float4*)&gr[i * 1024 + tid * 4];
    const float gvv[4] = { gv.x, gv.y, gv.z, gv.w };
    u16 out[4];
#pragma unroll
    for (int j = 0; j < 4; ++j) {
      const int f = i * 1024 + tid * 4 + j;
      float sval = 0.f;
      if (flag[f]) {
        const float zz = zreg[i * 4 + j];
        sval = (zz / (1.f + expf(-zz))) * gvv[j];
      }
      out[j] = f2bf(sval);
    }
    *(ushort4*)&srow[i * 1024 + tid * 4] = make_ushort4(out[0], out[1], out[2], out[3]);
  }
}

// ---------------- launch ----------------
extern "C" void kernel_launch(void* const* d_in, const int* in_sizes, int n_in,
                              void* d_out, int out_size, void* d_ws, size_t ws_size,
                              hipStream_t stream)
{
  const float* x  = (const float*)d_in[0];
  const float* W1 = (const float*)d_in[1];
  const float* W2 = (const float*)d_in[2];
  const float* Wo = (const float*)d_in[3];
  const int* kptr = (const int*)d_in[4];

  const int DM = 1024, DF = 4096;
  const int M = in_sizes[0] / DM;   // 8192 rows
  const size_t nX = (size_t)M * DM, nW = (size_t)DF * DM, nWo = (size_t)DM * DF;

  // fixed split buffers
  char* w = (char*)d_ws;
  u16* x_hi  = (u16*)w;  w += nX * 2;
  u16* x_lo  = (u16*)w;  w += nX * 2;
  u16* W1_hi = (u16*)w;  w += nW * 2;
  u16* W1_lo = (u16*)w;  w += nW * 2;
  u16* W2_hi = (u16*)w;  w += nW * 2;
  u16* Wo_hi = (u16*)w;  w += nWo * 2;
  const size_t fixed_bytes = (size_t)(w - (char*)d_ws);

  // per-chunk activations: z(4) + g(4) + s(2) = 10 B/elem
  int nch = 1;
  while (nch < 64) {
    const size_t per = (size_t)(M / nch) * DF * 10;
    if (fixed_bytes + per <= ws_size) break;
    nch *= 2;
  }
  const int Mc = M / nch;

  float* zbuf = (float*)w;
  float* gbuf = (float*)(w + (size_t)Mc * DF * 4);
  u16*   sbuf = (u16*)(w + (size_t)Mc * DF * 8);

  split2_kernel<<<dim3((int)((nX + 255) / 256)), 256, 0, stream>>>(x, x_hi, x_lo, (int)nX);
  split2_kernel<<<dim3((int)((nW + 255) / 256)), 256, 0, stream>>>(W1, W1_hi, W1_lo, (int)nW);
  split1_kernel<<<dim3((int)((nW + 255) / 256)), 256, 0, stream>>>(W2, W2_hi, (int)nW);
  split1_kernel<<<dim3((int)((nWo + 255) / 256)), 256, 0, stream>>>(Wo, Wo_hi, (int)nWo);

  for (int ch = 0; ch < nch; ++ch) {
    const size_t ro = (size_t)ch * Mc;
    // z = x @ W1^T (split precision as one K'=3072 GEMM: selection-grade)
    gemmz_kernel<64><<<dim3(DF / 128, Mc / 128), 256, 0, stream>>>(
        x_hi + ro * DM, x_lo + ro * DM, W1_hi, W1_lo, zbuf, DF, DM);
    // gate = x @ W2^T (1-pass bf16)
    gemm_bt<64><<<dim3(DF / 128, Mc / 128), 256, 0, stream>>>(
        x_hi + ro * DM, W2_hi, gbuf, DF, DM);
    // top-k: register bisection + band replica + stable ties
    select4_kernel<<<dim3(Mc), 256, 0, stream>>>(
        zbuf, gbuf, x + ro * DM, W1, sbuf, kptr);
    // out = s @ Wo^T (1-pass bf16)
    gemm_bt<64><<<dim3(DM / 128, Mc / 128), 256, 0, stream>>>(
        sbuf, Wo_hi, (float*)d_out + ro * DM, DM, DF);
  }
}